// Round 3
// baseline (461.785 us; speedup 1.0000x reference)
//
#include <hip/hip_runtime.h>

#define B_ 4
#define N_ 4096
#define D_ 1024
#define R_ 32
#define BN_ (B_ * N_)

typedef __attribute__((ext_vector_type(8))) short short8;
typedef __attribute__((ext_vector_type(4))) float f32x4;

// round-to-nearest-even fp32 -> bf16
__device__ inline unsigned int f2bf(float f) {
  unsigned int u = __float_as_uint(f);
  return (u + 0x7fffu + ((u >> 16) & 1u)) >> 16;
}

// packed RNE fp32x2 -> bf16x2 in one VALU op
__device__ inline unsigned int cvt_pk_bf16(float lo, float hi) {
  unsigned int r;
  asm("v_cvt_pk_bf16_f32 %0, %1, %2" : "=v"(r) : "v"(lo), "v"(hi));
  return r;
}

// swap lanes 0<->1, 2<->3 (pairs ln^1) on the VALU pipe (DPP quad_perm [1,0,3,2])
__device__ inline float dpp_swap1(float x) {
  return __int_as_float(
      __builtin_amdgcn_mov_dpp(__float_as_int(x), 0xB1, 0xF, 0xF, true));
}

// ---------------------------------------------------------------------------
// prep_kernel: MERGED uv (split-bf16 MFMA) + vT transpose. Both HBM-bound;
// merging co-fills the machine and saves a launch gap.
// grid: 512 uv-blocks (bid<512) + 4096 vT-blocks. 256 thr.
// ---------------------------------------------------------------------------
#define UV_GS 136
#define UV_RS 552   // 4*UV_GS + 8

__global__ __launch_bounds__(256) void prep_kernel(
    const float* __restrict__ q, const float* __restrict__ kmat,
    const float* __restrict__ v,
    const float* __restrict__ Wu, const float* __restrict__ Wv,
    unsigned short* __restrict__ u, unsigned short* __restrict__ vp,
    unsigned short* __restrict__ vT)
{
  __shared__ __align__(16) unsigned char smem[27648];
  const int t = threadIdx.x;
  const int bid = blockIdx.x;

  if (bid < 512) {
    // ---------------- uv part: u = (q@Wu)*log2e/sqrt(R), vp = k@Wv ----------
    unsigned short* ah_lds = (unsigned short*)smem;          // 8*UV_RS
    unsigned short* al_lds = ah_lds + 8 * UV_RS;             // 8*UV_RS
    unsigned short* wth    = al_lds + 8 * UV_RS;             // [32][72]
    unsigned short* wtl    = wth + 32 * 72;                  // [32][72]

    const int by = bid >> 8;          // 0: q->u, 1: k->vp
    const int bx = bid & 255;
    const float* __restrict__ x = (by == 0) ? q : kmat;
    const float* __restrict__ W = (by == 0) ? Wu : Wv;
    unsigned short* __restrict__ o = (by == 0) ? u : vp;
    const float osc = (by == 0)
        ? (0.17677669529663687f * 1.4426950408889634f) : 1.0f;

    const int r0 = bx * 64;
    const int lane = t & 63;
    const int w = t >> 6;
    const int qd = lane >> 4;
    const int ln = lane & 15;

    f32x4 acc[2];
#pragma unroll
    for (int ct = 0; ct < 2; ++ct)
#pragma unroll
      for (int i = 0; i < 4; ++i) acc[ct][i] = 0.f;

    const int a_rd = qd * UV_GS + ln * 8;

    for (int k0 = 0; k0 < D_; k0 += 64) {
#pragma unroll
      for (int i = 0; i < 4; ++i) {
        int idx = t + i * 256;
        int row = idx >> 4;
        int kc = (idx & 15) * 4;
        float4 f = *(const float4*)&x[(size_t)(r0 + row) * D_ + k0 + kc];
        int fr = (row >> 4) * 2 + (kc >> 5);
        int off = fr * UV_RS + ((kc >> 3) & 3) * UV_GS + (row & 15) * 8 + (kc & 7);
        unsigned int h01 = cvt_pk_bf16(f.x, f.y);
        unsigned int h23 = cvt_pk_bf16(f.z, f.w);
        float hx = __uint_as_float(h01 << 16);
        float hy = __uint_as_float(h01 & 0xffff0000u);
        float hz = __uint_as_float(h23 << 16);
        float hw = __uint_as_float(h23 & 0xffff0000u);
        unsigned int l01 = cvt_pk_bf16(f.x - hx, f.y - hy);
        unsigned int l23 = cvt_pk_bf16(f.z - hz, f.w - hw);
        *(unsigned int*)&ah_lds[off]     = h01;
        *(unsigned int*)&ah_lds[off + 2] = h23;
        *(unsigned int*)&al_lds[off]     = l01;
        *(unsigned int*)&al_lds[off + 2] = l23;
      }
#pragma unroll
      for (int i = 0; i < 2; ++i) {
        int idx = t + i * 256;
        int kr = idx >> 3;
        int cc = (idx & 7) * 4;
        float4 fw = *(const float4*)&W[(size_t)(k0 + kr) * R_ + cc];
        float vv[4] = {fw.x, fw.y, fw.z, fw.w};
#pragma unroll
        for (int j = 0; j < 4; ++j) {
          unsigned int hb = f2bf(vv[j]);
          wth[(cc + j) * 72 + kr] = (unsigned short)hb;
          float lo = vv[j] - __uint_as_float(hb << 16);
          wtl[(cc + j) * 72 + kr] = (unsigned short)f2bf(lo);
        }
      }
      __syncthreads();

      short8 bh[2][2], bl[2][2];
#pragma unroll
      for (int ct = 0; ct < 2; ++ct)
#pragma unroll
        for (int ks = 0; ks < 2; ++ks) {
          bh[ct][ks] = *(const short8*)&wth[(ct * 16 + ln) * 72 + ks * 32 + qd * 8];
          bl[ct][ks] = *(const short8*)&wtl[(ct * 16 + ln) * 72 + ks * 32 + qd * 8];
        }

#pragma unroll
      for (int ks = 0; ks < 2; ++ks) {
        short8 ah = *(const short8*)&ah_lds[(w * 2 + ks) * UV_RS + a_rd];
        short8 al = *(const short8*)&al_lds[(w * 2 + ks) * UV_RS + a_rd];
#pragma unroll
        for (int ct = 0; ct < 2; ++ct) {
          acc[ct] = __builtin_amdgcn_mfma_f32_16x16x32_bf16(ah, bh[ct][ks], acc[ct], 0, 0, 0);
          acc[ct] = __builtin_amdgcn_mfma_f32_16x16x32_bf16(ah, bl[ct][ks], acc[ct], 0, 0, 0);
          acc[ct] = __builtin_amdgcn_mfma_f32_16x16x32_bf16(al, bh[ct][ks], acc[ct], 0, 0, 0);
        }
      }
      __syncthreads();
    }

#pragma unroll
    for (int ct = 0; ct < 2; ++ct)
#pragma unroll
      for (int i = 0; i < 4; ++i) {
        int row = r0 + w * 16 + qd * 4 + i;
        o[(size_t)row * R_ + ct * 16 + ln] = (unsigned short)f2bf(acc[ct][i] * osc);
      }
  } else {
    // ---------------- vT part: vT[b][d][key] = bf16(v[b][key][d]) ----------
    unsigned short* tile = (unsigned short*)smem;  // [64][72]
    const int r = bid - 512;
    const int key0 = (r & 63) * 64;
    const int d0 = ((r >> 6) & 15) * 64;
    const int b = r >> 10;
    const float* vb = v + (size_t)b * N_ * D_;

#pragma unroll
    for (int i = 0; i < 4; ++i) {
      int kl = (t >> 4) + 16 * i;
      int dl = (t & 15) * 4;
      float4 f = *(const float4*)&vb[(size_t)(key0 + kl) * D_ + d0 + dl];
      tile[(dl + 0) * 72 + kl] = (unsigned short)f2bf(f.x);
      tile[(dl + 1) * 72 + kl] = (unsigned short)f2bf(f.y);
      tile[(dl + 2) * 72 + kl] = (unsigned short)f2bf(f.z);
      tile[(dl + 3) * 72 + kl] = (unsigned short)f2bf(f.w);
    }
    __syncthreads();
    unsigned short* ob = vT + (size_t)b * D_ * N_;
#pragma unroll
    for (int i = 0; i < 2; ++i) {
      int dl = (t >> 3) + 32 * i;
      int kc = (t & 7) * 8;
      *(short8*)&ob[(size_t)(d0 + dl) * N_ + key0 + kc] =
          *(const short8*)&tile[dl * 72 + kc];
    }
  }
}

// ---------------------------------------------------------------------------
// Kernel 3 (fused flash, v3 pipelined): out[b,q0:+128,d0:+256]=softmax(u vp^T)@V
// 512 thr / 8 waves; wave w owns d-slice d0+32w..+32 (PV) and q-rows
// q0+16w..+16 (S/softmax). Double-buffered P in LDS; ONE barrier per iter.
// Per iter: S(t+1) MFMA (vpf prefetched last iter, lands during barrier) ->
// afr ds_reads -> interleaved [softmax-slice(t+1) VALU | PV(t) MFMA chunk]
// -> next-tile global loads (reg-staged, ride across the barrier) -> barrier.
// grid (B, D/256, N/128).
// ---------------------------------------------------------------------------
#define PBUF (128 * 72)

__global__ __launch_bounds__(512, 2) void fused_attn_kernel(
    const unsigned short* __restrict__ ub, const unsigned short* __restrict__ vpb,
    const unsigned short* __restrict__ vT, float* __restrict__ out)
{
  __shared__ __align__(16) unsigned short plds[2 * PBUF];  // 36.9 KB
  __shared__ float l_lds[128];

  const int t = threadIdx.x;
  const int lane = t & 63;
  const int w = t >> 6;          // 0..7
  const int qd = lane >> 4;
  const int ln = lane & 15;

  const int b  = blockIdx.x;
  const int d0 = blockIdx.y * 256;
  const int q0 = blockIdx.z * 128;

  const unsigned short* uB  = ub  + (size_t)b * N_ * R_;
  const unsigned short* vpB = vpb + (size_t)b * N_ * R_;
  const unsigned short* vTw = vT + (size_t)b * D_ * N_ + (size_t)(d0 + w * 32) * N_;

  // S-phase A-frag: wave w covers q-rows q0+16w..+16 (one 16-row frag)
  const short8 ufrag = *(const short8*)&uB[(size_t)(q0 + 16 * w + ln) * R_ + qd * 8];

  f32x4 acc[8][2];
#pragma unroll
  for (int rg = 0; rg < 8; ++rg)
#pragma unroll
    for (int ct = 0; ct < 2; ++ct)
#pragma unroll
      for (int i = 0; i < 4; ++i) acc[rg][ct][i] = 0.f;

  float l_acc[4];
#pragma unroll
  for (int r = 0; r < 4; ++r) l_acc[r] = 0.f;

  // ---- prologue: S(0)+softmax(0) -> plds[0]; prefetch vpf(1), bfr(0) ----
  short8 vpf[4];
#pragma unroll
  for (int c = 0; c < 4; ++c)
    vpf[c] = *(const short8*)&vpB[(size_t)(c * 16 + ln) * R_ + qd * 8];

  f32x4 sacc[4];
#pragma unroll
  for (int c = 0; c < 4; ++c) {
#pragma unroll
    for (int i = 0; i < 4; ++i) sacc[c][i] = 0.f;
    sacc[c] = __builtin_amdgcn_mfma_f32_16x16x32_bf16(ufrag, vpf[c], sacc[c], 0, 0, 0);
  }
#pragma unroll
  for (int c = 0; c < 4; ++c) {
#pragma unroll
    for (int r = 0; r < 4; ++r) {
      float p = exp2f(sacc[c][r]);
      l_acc[r] += p;
      float pq = dpp_swap1(p);
      if ((ln & 1) == 0)
        *(unsigned int*)&plds[(16 * w + qd * 4 + r) * 72 + c * 16 + (ln & 14)] =
            cvt_pk_bf16(p, pq);
    }
  }
  // prefetch for pipeline: vpf <- vp(tile1), bfr <- vT(tile0)
#pragma unroll
  for (int c = 0; c < 4; ++c)
    vpf[c] = *(const short8*)&vpB[(size_t)(64 + c * 16 + ln) * R_ + qd * 8];
  short8 bfr[2][2];
#pragma unroll
  for (int ct = 0; ct < 2; ++ct)
#pragma unroll
    for (int s = 0; s < 2; ++s)
      bfr[ct][s] = *(const short8*)&vTw[(size_t)(ct * 16 + ln) * N_ + s * 32 + qd * 8];
  __syncthreads();

  // ---- main loop: 63 full iters (PV(t) + S/softmax(t+1)), then tail ----
  for (int tt = 0; tt < 63; ++tt) {
    const int k0 = tt * 64;
    const unsigned short* prd = plds + (tt & 1) * PBUF;
    unsigned short* pwr = plds + ((tt + 1) & 1) * PBUF;

    // S(t+1): 4 MFMA on prefetched vpf
#pragma unroll
    for (int c = 0; c < 4; ++c) {
#pragma unroll
      for (int i = 0; i < 4; ++i) sacc[c][i] = 0.f;
      sacc[c] = __builtin_amdgcn_mfma_f32_16x16x32_bf16(ufrag, vpf[c], sacc[c], 0, 0, 0);
    }

    // afr: P(t) fragments, all 128 q-rows
    short8 afr[8][2];
#pragma unroll
    for (int rg = 0; rg < 8; ++rg)
#pragma unroll
      for (int s = 0; s < 2; ++s)
        afr[rg][s] = *(const short8*)&prd[(rg * 16 + ln) * 72 + s * 32 + qd * 8];

    __builtin_amdgcn_s_setprio(1);
    // interleave: softmax slice c (VALU) | PV chunk c (4 MFMA, s=0)
#pragma unroll
    for (int c = 0; c < 4; ++c) {
#pragma unroll
      for (int r = 0; r < 4; ++r) {
        float p = exp2f(sacc[c][r]);
        l_acc[r] += p;
        float pq = dpp_swap1(p);
        if ((ln & 1) == 0)
          *(unsigned int*)&pwr[(16 * w + qd * 4 + r) * 72 + c * 16 + (ln & 14)] =
              cvt_pk_bf16(p, pq);
      }
#pragma unroll
      for (int g = 0; g < 2; ++g) {
        const int rg = 2 * c + g;
        acc[rg][0] = __builtin_amdgcn_mfma_f32_16x16x32_bf16(afr[rg][0], bfr[0][0], acc[rg][0], 0, 0, 0);
        acc[rg][1] = __builtin_amdgcn_mfma_f32_16x16x32_bf16(afr[rg][0], bfr[1][0], acc[rg][1], 0, 0, 0);
      }
    }
    // remaining PV chunks (s=1)
#pragma unroll
    for (int rg = 0; rg < 8; ++rg) {
      acc[rg][0] = __builtin_amdgcn_mfma_f32_16x16x32_bf16(afr[rg][1], bfr[0][1], acc[rg][0], 0, 0, 0);
      acc[rg][1] = __builtin_amdgcn_mfma_f32_16x16x32_bf16(afr[rg][1], bfr[1][1], acc[rg][1], 0, 0, 0);
    }
    __builtin_amdgcn_s_setprio(0);

    // issue next-tile globals (consumed next iter; ride across the barrier)
    {
      const int kv = (k0 + 128 <= N_ - 64) ? (k0 + 128) : (N_ - 64);  // clamp, unused at tail
#pragma unroll
      for (int c = 0; c < 4; ++c)
        vpf[c] = *(const short8*)&vpB[(size_t)(kv + c * 16 + ln) * R_ + qd * 8];
      const int kb = k0 + 64;
#pragma unroll
      for (int ct = 0; ct < 2; ++ct)
#pragma unroll
        for (int s = 0; s < 2; ++s)
          bfr[ct][s] = *(const short8*)&vTw[(size_t)(ct * 16 + ln) * N_ + kb + s * 32 + qd * 8];
    }
    __syncthreads();
  }

  // ---- tail: PV(63) ----
  {
    const unsigned short* prd = plds + PBUF;  // 63&1 = 1
    short8 afr[8][2];
#pragma unroll
    for (int rg = 0; rg < 8; ++rg)
#pragma unroll
      for (int s = 0; s < 2; ++s)
        afr[rg][s] = *(const short8*)&prd[(rg * 16 + ln) * 72 + s * 32 + qd * 8];
#pragma unroll
    for (int rg = 0; rg < 8; ++rg)
#pragma unroll
      for (int s = 0; s < 2; ++s) {
        acc[rg][0] = __builtin_amdgcn_mfma_f32_16x16x32_bf16(afr[rg][s], bfr[0][s], acc[rg][0], 0, 0, 0);
        acc[rg][1] = __builtin_amdgcn_mfma_f32_16x16x32_bf16(afr[rg][s], bfr[1][s], acc[rg][1], 0, 0, 0);
      }
  }

  // ---- l: reduce over the 16 lanes of each quad-row group ----
#pragma unroll
  for (int r = 0; r < 4; ++r) {
    float v = l_acc[r];
    v += __shfl_xor(v, 1);
    v += __shfl_xor(v, 2);
    v += __shfl_xor(v, 4);
    v += __shfl_xor(v, 8);
    if (ln == 0) l_lds[16 * w + qd * 4 + r] = v;
  }
  __syncthreads();

  // ---- epilogue: out = acc / l ----
#pragma unroll
  for (int rg = 0; rg < 8; ++rg) {
#pragma unroll
    for (int r = 0; r < 4; ++r) {
      const int row = rg * 16 + qd * 4 + r;
      const float inv = 1.0f / l_lds[row];
      float* orow = out + ((size_t)b * N_ + q0 + row) * D_ + d0 + w * 32;
#pragma unroll
      for (int ct = 0; ct < 2; ++ct)
        orow[ct * 16 + ln] = acc[rg][ct][r] * inv;
    }
  }
}

// ---------------------------------------------------------------------------
// Fallback (R1, known-good fp32 fused) — used only if ws too small.
// ---------------------------------------------------------------------------
__global__ __launch_bounds__(256) void uv_gemm_f32(
    const float* __restrict__ q, const float* __restrict__ kmat,
    const float* __restrict__ Wu, const float* __restrict__ Wv,
    float* __restrict__ u, float* __restrict__ vp)
{
  __shared__ float x_lds[64][68];
  __shared__ float w_lds[64][36];
  const int t = threadIdx.x;
  const float* __restrict__ x = (blockIdx.y == 0) ? q : kmat;
  const float* __restrict__ W = (blockIdx.y == 0) ? Wu : Wv;
  float* __restrict__ o = (blockIdx.y == 0) ? u : vp;
  const int m0 = blockIdx.x * 64;
  const int row = t >> 2;
  const int c0 = (t & 3) * 8;
  float acc[8];
#pragma unroll
  for (int i = 0; i < 8; ++i) acc[i] = 0.f;
  for (int k0 = 0; k0 < D_; k0 += 64) {
#pragma unroll
    for (int i = 0; i < 4; ++i) {
      int f4 = t + i * 256;
      int r_ = f4 >> 4, cc = (f4 & 15) * 4;
      *(float4*)&x_lds[r_][cc] = *(const float4*)&x[(size_t)(m0 + r_) * D_ + k0 + cc];
    }
#pragma unroll
    for (int i = 0; i < 2; ++i) {
      int f4 = t + i * 256;
      int r_ = f4 >> 3, cc = (f4 & 7) * 4;
      *(float4*)&w_lds[r_][cc] = *(const float4*)&W[(size_t)(k0 + r_) * R_ + cc];
    }
    __syncthreads();
#pragma unroll 8
    for (int kk = 0; kk < 64; ++kk) {
      float a = x_lds[row][kk];
      float4 b0 = *(float4*)&w_lds[kk][c0];
      float4 b1 = *(float4*)&w_lds[kk][c0 + 4];
      acc[0] = fmaf(a, b0.x, acc[0]); acc[1] = fmaf(a, b0.y, acc[1]);
      acc[2] = fmaf(a, b0.z, acc[2]); acc[3] = fmaf(a, b0.w, acc[3]);
      acc[4] = fmaf(a, b1.x, acc[4]); acc[5] = fmaf(a, b1.y, acc[5]);
      acc[6] = fmaf(a, b1.z, acc[6]); acc[7] = fmaf(a, b1.w, acc[7]);
    }
    __syncthreads();
  }
  *(float4*)&o[(size_t)(m0 + row) * R_ + c0] = make_float4(acc[0], acc[1], acc[2], acc[3]);
  *(float4*)&o[(size_t)(m0 + row) * R_ + c0 + 4] = make_float4(acc[4], acc[5], acc[6], acc[7]);
}

__global__ __launch_bounds__(256) void attn_kernel(
    const float* __restrict__ u, const float* __restrict__ vp,
    const float* __restrict__ v, float* __restrict__ out)
{
  __shared__ float u_lds[64][36];
  __shared__ float vpT_lds[32][36];
  __shared__ float p_lds[64][36];
  __shared__ float v_lds[32][132];
  __shared__ float l_lds[64];
  const int t = threadIdx.x;
  const int b = blockIdx.z;
  const int m0 = blockIdx.x * 64;
  const int d0 = blockIdx.y * 128;
  const size_t rb = (size_t)b * N_;
#pragma unroll
  for (int i = 0; i < 2; ++i) {
    int f4 = t + i * 256;
    int r_ = f4 >> 3, cc = (f4 & 7) * 4;
    *(float4*)&u_lds[r_][cc] = *(const float4*)&u[(rb + m0 + r_) * R_ + cc];
  }
  const int srow = t >> 2;
  const int kc0 = (t & 3) * 8;
  const int rg = t >> 5;
  const int cx = t & 31;
  float acc[8][4];
#pragma unroll
  for (int i = 0; i < 8; ++i)
#pragma unroll
    for (int j = 0; j < 4; ++j) acc[i][j] = 0.f;
  float l_part = 0.f;
  const float scale = 0.17677669529663687f;
  for (int k0 = 0; k0 < N_; k0 += 32) {
    {
      int r_ = t >> 3, cc = (t & 7) * 4;
      float4 w4 = *(const float4*)&vp[(rb + k0 + r_) * R_ + cc];
      vpT_lds[cc + 0][r_] = w4.x; vpT_lds[cc + 1][r_] = w4.y;
      vpT_lds[cc + 2][r_] = w4.z; vpT_lds[cc + 3][r_] = w4.w;
    }
#pragma unroll
    for (int i = 0; i < 4; ++i) {
      int f4 = t + i * 256;
      int r_ = f4 >> 5, cc = (f4 & 31) * 4;
      *(float4*)&v_lds[r_][cc] = *(const float4*)&v[(rb + k0 + r_) * D_ + d0 + cc];
    }
    __syncthreads();
    float s[8];
#pragma unroll
    for (int j = 0; j < 8; ++j) s[j] = 0.f;
#pragma unroll
    for (int rr = 0; rr < 32; rr += 4) {
      float4 u4 = *(float4*)&u_lds[srow][rr];
      float ua[4] = {u4.x, u4.y, u4.z, u4.w};
#pragma unroll
      for (int q4 = 0; q4 < 4; ++q4) {
        float uu = ua[q4];
        float4 g0 = *(float4*)&vpT_lds[rr + q4][kc0];
        float4 g1 = *(float4*)&vpT_lds[rr + q4][kc0 + 4];
        s[0] = fmaf(uu, g0.x, s[0]); s[1] = fmaf(uu, g0.y, s[1]);
        s[2] = fmaf(uu, g0.z, s[2]); s[3] = fmaf(uu, g0.w, s[3]);
        s[4] = fmaf(uu, g1.x, s[4]); s[5] = fmaf(uu, g1.y, s[5]);
        s[6] = fmaf(uu, g1.z, s[6]); s[7] = fmaf(uu, g1.w, s[7]);
      }
    }
    float p[8];
    float lsum = 0.f;
#pragma unroll
    for (int j = 0; j < 8; ++j) { p[j] = __expf(s[j] * scale); lsum += p[j]; }
    l_part += lsum;
    *(float4*)&p_lds[srow][kc0] = make_float4(p[0], p[1], p[2], p[3]);
    *(float4*)&p_lds[srow][kc0 + 4] = make_float4(p[4], p[5], p[6], p[7]);
    __syncthreads();
#pragma unroll 4
    for (int kk = 0; kk < 32; ++kk) {
      float4 bv = *(float4*)&v_lds[kk][cx * 4];
#pragma unroll
      for (int i = 0; i < 8; ++i) {
        float a = p_lds[rg * 8 + i][kk];
        acc[i][0] = fmaf(a, bv.x, acc[i][0]); acc[i][1] = fmaf(a, bv.y, acc[i][1]);
        acc[i][2] = fmaf(a, bv.z, acc[i][2]); acc[i][3] = fmaf(a, bv.w, acc[i][3]);
      }
    }
    __syncthreads();
  }
  l_part += __shfl_xor(l_part, 1);
  l_part += __shfl_xor(l_part, 2);
  if ((t & 3) == 0) l_lds[srow] = l_part;
  __syncthreads();
#pragma unroll
  for (int i = 0; i < 8; ++i) {
    int row = rg * 8 + i;
    float inv = 1.0f / l_lds[row];
    *(float4*)&out[(rb + m0 + row) * D_ + d0 + cx * 4] =
        make_float4(acc[i][0] * inv, acc[i][1] * inv, acc[i][2] * inv, acc[i][3] * inv);
  }
}

// ---------------------------------------------------------------------------
extern "C" void kernel_launch(void* const* d_in, const int* in_sizes, int n_in,
                              void* d_out, int out_size, void* d_ws, size_t ws_size,
                              hipStream_t stream) {
  const float* q  = (const float*)d_in[0];
  const float* k  = (const float*)d_in[1];
  const float* v  = (const float*)d_in[2];
  const float* Wu = (const float*)d_in[3];
  const float* Wv = (const float*)d_in[4];
  float* out = (float*)d_out;

  // ws layout: u_bf 1MB | vp_bf 1MB | vT 32MiB  (~35.6 MB total)
  const size_t o_u  = 0;
  const size_t o_vp = (size_t)1 << 20;
  const size_t o_vt = (size_t)2 << 20;
  const size_t vt_bytes = (size_t)B_ * D_ * N_ * 2;
  const size_t need = o_vt + vt_bytes;

  if (ws_size >= need) {
    unsigned short* ub  = (unsigned short*)((char*)d_ws + o_u);
    unsigned short* vpb = (unsigned short*)((char*)d_ws + o_vp);
    unsigned short* vtb = (unsigned short*)((char*)d_ws + o_vt);

    prep_kernel<<<dim3(512 + 4096), 256, 0, stream>>>(q, k, v, Wu, Wv, ub, vpb, vtb);
    fused_attn_kernel<<<dim3(B_, D_ / 256, N_ / 128), 512, 0, stream>>>(
        ub, vpb, vtb, out);
  } else {
    float* uf  = (float*)d_ws;
    float* vpf = uf + (size_t)BN_ * R_;
    uv_gemm_f32<<<dim3(BN_ / 64, 2), 256, 0, stream>>>(q, k, Wu, Wv, uf, vpf);
    attn_kernel<<<dim3(N_ / 64, D_ / 128, B_), 256, 0, stream>>>(uf, vpf, v, out);
  }
}

// Round 4
// 424.484 us; speedup vs baseline: 1.0879x; 1.0879x over previous
//
#include <hip/hip_runtime.h>

#define B_ 4
#define N_ 4096
#define D_ 1024
#define R_ 32
#define BN_ (B_ * N_)

typedef __attribute__((ext_vector_type(8))) short short8;
typedef __attribute__((ext_vector_type(4))) float f32x4;

// round-to-nearest-even fp32 -> bf16
__device__ inline unsigned int f2bf(float f) {
  unsigned int u = __float_as_uint(f);
  return (u + 0x7fffu + ((u >> 16) & 1u)) >> 16;
}

// packed RNE fp32x2 -> bf16x2 in one VALU op
__device__ inline unsigned int cvt_pk_bf16(float lo, float hi) {
  unsigned int r;
  asm("v_cvt_pk_bf16_f32 %0, %1, %2" : "=v"(r) : "v"(lo), "v"(hi));
  return r;
}

// swap lanes 0<->1, 2<->3 (pairs ln^1) on the VALU pipe (DPP quad_perm [1,0,3,2])
__device__ inline float dpp_swap1(float x) {
  return __int_as_float(
      __builtin_amdgcn_mov_dpp(__float_as_int(x), 0xB1, 0xF, 0xF, true));
}

// ---------------------------------------------------------------------------
// Kernel 1: u = (q @ Wu) * log2e/sqrt(R), vp = k @ Wv via split-bf16 MFMA.
//   x = xh + xl (two RNE bf16 halves), W likewise; u = xh*Wh + xh*Wl + xl*Wh
// HBM-bound (~134 MB reads).  grid (BN/64, 2), 256 thr.  (R2-validated)
// ---------------------------------------------------------------------------
#define UV_GS 136
#define UV_RS 552   // 4*UV_GS + 8

__global__ __launch_bounds__(256) void uv_mfma_kernel(
    const float* __restrict__ q, const float* __restrict__ kmat,
    const float* __restrict__ Wu, const float* __restrict__ Wv,
    unsigned short* __restrict__ u, unsigned short* __restrict__ vp)
{
  __shared__ unsigned short ah_lds[8 * UV_RS];   // hi A-frags, 8 regions
  __shared__ unsigned short al_lds[8 * UV_RS];   // lo A-frags
  __shared__ unsigned short wth[32][72];         // W^T hi  [col][k], pad 8
  __shared__ unsigned short wtl[32][72];         // W^T lo

  const int t = threadIdx.x;
  const float* __restrict__ x = (blockIdx.y == 0) ? q : kmat;
  const float* __restrict__ W = (blockIdx.y == 0) ? Wu : Wv;
  unsigned short* __restrict__ o = (blockIdx.y == 0) ? u : vp;
  // 1/sqrt(32) * log2(e): fold softmax scale + exp->exp2 conversion into u
  const float osc = (blockIdx.y == 0)
      ? (0.17677669529663687f * 1.4426950408889634f) : 1.0f;

  const int r0 = blockIdx.x * 64;
  const int lane = t & 63;
  const int w = t >> 6;        // wave id == rowtile rt
  const int qd = lane >> 4;
  const int ln = lane & 15;

  f32x4 acc[2];
#pragma unroll
  for (int ct = 0; ct < 2; ++ct)
#pragma unroll
    for (int i = 0; i < 4; ++i) acc[ct][i] = 0.f;

  const int a_rd = qd * UV_GS + ln * 8;  // per-lane offset inside a region

  for (int k0 = 0; k0 < D_; k0 += 64) {
    // ---- stage x tile (64 rows x 64 k f32), split to bf16 hi/lo A-frags ----
#pragma unroll
    for (int i = 0; i < 4; ++i) {
      int idx = t + i * 256;          // 0..1023
      int row = idx >> 4;             // 0..63
      int kc = (idx & 15) * 4;        // 0..60
      float4 f = *(const float4*)&x[(size_t)(r0 + row) * D_ + k0 + kc];
      int fr = (row >> 4) * 2 + (kc >> 5);
      int off = fr * UV_RS + ((kc >> 3) & 3) * UV_GS + (row & 15) * 8 + (kc & 7);
      unsigned int h01 = cvt_pk_bf16(f.x, f.y);
      unsigned int h23 = cvt_pk_bf16(f.z, f.w);
      float hx = __uint_as_float(h01 << 16);
      float hy = __uint_as_float(h01 & 0xffff0000u);
      float hz = __uint_as_float(h23 << 16);
      float hw = __uint_as_float(h23 & 0xffff0000u);
      unsigned int l01 = cvt_pk_bf16(f.x - hx, f.y - hy);
      unsigned int l23 = cvt_pk_bf16(f.z - hz, f.w - hw);
      *(unsigned int*)&ah_lds[off]     = h01;
      *(unsigned int*)&ah_lds[off + 2] = h23;
      *(unsigned int*)&al_lds[off]     = l01;
      *(unsigned int*)&al_lds[off + 2] = l23;
    }
    // ---- stage W chunk transposed: [k][32] f32 -> W^T hi/lo [col][k] bf16 ----
#pragma unroll
    for (int i = 0; i < 2; ++i) {
      int idx = t + i * 256;          // 0..511
      int kr = idx >> 3;              // 0..63
      int cc = (idx & 7) * 4;         // 0..28
      float4 fw = *(const float4*)&W[(size_t)(k0 + kr) * R_ + cc];
      float vv[4] = {fw.x, fw.y, fw.z, fw.w};
#pragma unroll
      for (int j = 0; j < 4; ++j) {
        unsigned int hb = f2bf(vv[j]);
        wth[cc + j][kr] = (unsigned short)hb;
        float lo = vv[j] - __uint_as_float(hb << 16);
        wtl[cc + j][kr] = (unsigned short)f2bf(lo);
      }
    }
    __syncthreads();

    // ---- B-frags (tiny W) to registers for this k-tile ----
    short8 bh[2][2], bl[2][2];        // [coltile][kstep]
#pragma unroll
    for (int ct = 0; ct < 2; ++ct)
#pragma unroll
      for (int ks = 0; ks < 2; ++ks) {
        bh[ct][ks] = *(const short8*)&wth[ct * 16 + ln][ks * 32 + qd * 8];
        bl[ct][ks] = *(const short8*)&wtl[ct * 16 + ln][ks * 32 + qd * 8];
      }

    // ---- MFMA: 2 ksteps x 2 coltiles x 3 split terms ----
#pragma unroll
    for (int ks = 0; ks < 2; ++ks) {
      short8 ah = *(const short8*)&ah_lds[(w * 2 + ks) * UV_RS + a_rd];
      short8 al = *(const short8*)&al_lds[(w * 2 + ks) * UV_RS + a_rd];
#pragma unroll
      for (int ct = 0; ct < 2; ++ct) {
        acc[ct] = __builtin_amdgcn_mfma_f32_16x16x32_bf16(ah, bh[ct][ks], acc[ct], 0, 0, 0);
        acc[ct] = __builtin_amdgcn_mfma_f32_16x16x32_bf16(ah, bl[ct][ks], acc[ct], 0, 0, 0);
        acc[ct] = __builtin_amdgcn_mfma_f32_16x16x32_bf16(al, bh[ct][ks], acc[ct], 0, 0, 0);
      }
    }
    __syncthreads();
  }

  // ---- epilogue: C layout col=ln, row=qd*4+i (validated convention) ----
#pragma unroll
  for (int ct = 0; ct < 2; ++ct)
#pragma unroll
    for (int i = 0; i < 4; ++i) {
      int row = r0 + w * 16 + qd * 4 + i;
      o[(size_t)row * R_ + ct * 16 + ln] = (unsigned short)f2bf(acc[ct][i] * osc);
    }
}

// ---------------------------------------------------------------------------
// Kernel 2: vT[b][d][key] = bf16(v[b][key][d]).  64x64 tiles via LDS.
// grid (N/64, D/64, B), 256 thr.  (validated)
// ---------------------------------------------------------------------------
__global__ __launch_bounds__(256) void vT_kernel(
    const float* __restrict__ v, unsigned short* __restrict__ vT)
{
  __shared__ unsigned short tile[64][72];
  const int t = threadIdx.x;
  const int key0 = blockIdx.x * 64;
  const int d0 = blockIdx.y * 64;
  const int b = blockIdx.z;
  const float* vb = v + (size_t)b * N_ * D_;

#pragma unroll
  for (int i = 0; i < 4; ++i) {
    int kl = (t >> 4) + 16 * i;
    int dl = (t & 15) * 4;
    float4 f = *(const float4*)&vb[(size_t)(key0 + kl) * D_ + d0 + dl];
    tile[dl + 0][kl] = (unsigned short)f2bf(f.x);
    tile[dl + 1][kl] = (unsigned short)f2bf(f.y);
    tile[dl + 2][kl] = (unsigned short)f2bf(f.z);
    tile[dl + 3][kl] = (unsigned short)f2bf(f.w);
  }
  __syncthreads();
  unsigned short* ob = vT + (size_t)b * D_ * N_;
#pragma unroll
  for (int i = 0; i < 2; ++i) {
    int dl = (t >> 3) + 32 * i;
    int kc = (t & 7) * 8;
    *(short8*)&ob[(size_t)(d0 + dl) * N_ + key0 + kc] =
        *(const short8*)&tile[dl][kc];
  }
}

// ---------------------------------------------------------------------------
// Kernel 3 (fused flash, v4): R2's proven 4-wave work split (wave w: S rows
// 32w..+32, PV d-slice 64w..+64 over all 128 q-rows; bfr straight from
// L2-resident vT) + pipelined schedule: double-buffered P in LDS, ONE
// barrier per iter, softmax(t+1) interleaved chunk-wise with PV(t) MFMAs.
// Traffic identical to R2 (FETCH ~18.5MB, conflicts ~8.4e6) — only the
// schedule changes. grid (B, D/256, N/128), 256 thr.
// ---------------------------------------------------------------------------
#define PBUF (128 * 72)

__global__ __launch_bounds__(256, 2) void fused_attn_kernel(
    const unsigned short* __restrict__ ub, const unsigned short* __restrict__ vpb,
    const unsigned short* __restrict__ vT, float* __restrict__ out)
{
  __shared__ __align__(16) unsigned short plds[2 * PBUF];  // 36.9 KB
  __shared__ float l_lds[128];

  const int t = threadIdx.x;
  const int lane = t & 63;
  const int w = t >> 6;          // 0..3
  const int qd = lane >> 4;
  const int ln = lane & 15;

  const int b  = blockIdx.x;
  const int d0 = blockIdx.y * 256;
  const int q0 = blockIdx.z * 128;

  const unsigned short* uB  = ub  + (size_t)b * N_ * R_;
  const unsigned short* vpB = vpb + (size_t)b * N_ * R_;
  const unsigned short* vTw = vT + (size_t)b * D_ * N_ + (size_t)(d0 + w * 64) * N_;

  // S-phase A-frags: wave w covers q-rows q0+32w..+32 (2 rowfrags)
  short8 ufrag[2];
#pragma unroll
  for (int rg2 = 0; rg2 < 2; ++rg2)
    ufrag[rg2] = *(const short8*)
        &uB[(size_t)(q0 + 32 * w + rg2 * 16 + ln) * R_ + qd * 8];

  f32x4 acc[8][4];
#pragma unroll
  for (int rg = 0; rg < 8; ++rg)
#pragma unroll
    for (int ct = 0; ct < 4; ++ct)
#pragma unroll
      for (int i = 0; i < 4; ++i) acc[rg][ct][i] = 0.f;

  float l_acc[2][4];
#pragma unroll
  for (int i = 0; i < 2; ++i)
#pragma unroll
    for (int j = 0; j < 4; ++j) l_acc[i][j] = 0.f;

  // ---- prologue: S(0)+softmax(0) -> plds[0]; prefetch vpf(1), bfr(0) ----
  short8 vpf[4];
#pragma unroll
  for (int c = 0; c < 4; ++c)
    vpf[c] = *(const short8*)&vpB[(size_t)(c * 16 + ln) * R_ + qd * 8];

  f32x4 sacc[2][4];
#pragma unroll
  for (int rg2 = 0; rg2 < 2; ++rg2)
#pragma unroll
    for (int c = 0; c < 4; ++c) {
#pragma unroll
      for (int i = 0; i < 4; ++i) sacc[rg2][c][i] = 0.f;
      sacc[rg2][c] = __builtin_amdgcn_mfma_f32_16x16x32_bf16(
          ufrag[rg2], vpf[c], sacc[rg2][c], 0, 0, 0);
    }
#pragma unroll
  for (int rg2 = 0; rg2 < 2; ++rg2)
#pragma unroll
    for (int c = 0; c < 4; ++c)
#pragma unroll
      for (int r = 0; r < 4; ++r) {
        float p = exp2f(sacc[rg2][c][r]);
        l_acc[rg2][r] += p;
        float pq = dpp_swap1(p);
        if ((ln & 1) == 0)
          *(unsigned int*)&plds[(32 * w + rg2 * 16 + qd * 4 + r) * 72 +
                                c * 16 + (ln & 14)] = cvt_pk_bf16(p, pq);
      }
  // prefetch for pipeline: vpf <- vp(tile1), bfr <- vT(tile0)
#pragma unroll
  for (int c = 0; c < 4; ++c)
    vpf[c] = *(const short8*)&vpB[(size_t)(64 + c * 16 + ln) * R_ + qd * 8];
  short8 bfr[4][2];
#pragma unroll
  for (int ct = 0; ct < 4; ++ct)
#pragma unroll
    for (int s = 0; s < 2; ++s)
      bfr[ct][s] = *(const short8*)&vTw[(size_t)(ct * 16 + ln) * N_ + s * 32 + qd * 8];
  __syncthreads();

  // ---- main loop: iters tt=0..62 do PV(tt) + S/softmax(tt+1); tail PV(63) ----
  for (int tt = 0; tt < 63; ++tt) {
    const int k0 = tt * 64;
    const unsigned short* prd = plds + (tt & 1) * PBUF;
    unsigned short* pwr = plds + ((tt + 1) & 1) * PBUF;

    // S(t+1): 8 MFMA on prefetched vpf
#pragma unroll
    for (int rg2 = 0; rg2 < 2; ++rg2)
#pragma unroll
      for (int c = 0; c < 4; ++c) {
#pragma unroll
        for (int i = 0; i < 4; ++i) sacc[rg2][c][i] = 0.f;
        sacc[rg2][c] = __builtin_amdgcn_mfma_f32_16x16x32_bf16(
            ufrag[rg2], vpf[c], sacc[rg2][c], 0, 0, 0);
      }

    __builtin_amdgcn_s_setprio(1);
    // interleaved halves: s=0 then s=1; within each, 4 chunks of
    // {softmax slice (rg2=s, ct2=c) | 8 PV MFMA}
#pragma unroll
    for (int s = 0; s < 2; ++s) {
      short8 afr[8];
#pragma unroll
      for (int rg = 0; rg < 8; ++rg)
        afr[rg] = *(const short8*)&prd[(rg * 16 + ln) * 72 + s * 32 + qd * 8];
#pragma unroll
      for (int c = 0; c < 4; ++c) {
        // softmax slice (rg2 = s, ct2 = c): 4 values
#pragma unroll
        for (int r = 0; r < 4; ++r) {
          float p = exp2f(sacc[s][c][r]);
          l_acc[s][r] += p;
          float pq = dpp_swap1(p);
          if ((ln & 1) == 0)
            *(unsigned int*)&pwr[(32 * w + s * 16 + qd * 4 + r) * 72 +
                                 c * 16 + (ln & 14)] = cvt_pk_bf16(p, pq);
        }
        // PV chunk: rows 2c,2c+1 x all 4 d-coltiles
#pragma unroll
        for (int g = 0; g < 2; ++g) {
          const int rg = 2 * c + g;
#pragma unroll
          for (int ct = 0; ct < 4; ++ct)
            acc[rg][ct] = __builtin_amdgcn_mfma_f32_16x16x32_bf16(
                afr[rg], bfr[ct][s], acc[rg][ct], 0, 0, 0);
        }
      }
    }
    __builtin_amdgcn_s_setprio(0);

    // issue next-tile globals (consumed next iter; ride across the barrier)
    {
      const int kv = (k0 + 128 <= N_ - 64) ? (k0 + 128) : (N_ - 64);
#pragma unroll
      for (int c = 0; c < 4; ++c)
        vpf[c] = *(const short8*)&vpB[(size_t)(kv + c * 16 + ln) * R_ + qd * 8];
      const int kb = k0 + 64;
#pragma unroll
      for (int ct = 0; ct < 4; ++ct)
#pragma unroll
        for (int s = 0; s < 2; ++s)
          bfr[ct][s] = *(const short8*)
              &vTw[(size_t)(ct * 16 + ln) * N_ + kb + s * 32 + qd * 8];
    }
    __syncthreads();
  }

  // ---- tail: PV(63) ----
  {
    const unsigned short* prd = plds + PBUF;  // 63&1 = 1
#pragma unroll
    for (int s = 0; s < 2; ++s) {
      short8 afr[8];
#pragma unroll
      for (int rg = 0; rg < 8; ++rg)
        afr[rg] = *(const short8*)&prd[(rg * 16 + ln) * 72 + s * 32 + qd * 8];
#pragma unroll
      for (int rg = 0; rg < 8; ++rg)
#pragma unroll
        for (int ct = 0; ct < 4; ++ct)
          acc[rg][ct] = __builtin_amdgcn_mfma_f32_16x16x32_bf16(
              afr[rg], bfr[ct][s], acc[rg][ct], 0, 0, 0);
    }
  }

  // ---- l: reduce over the 16 lanes of each quad-row group ----
#pragma unroll
  for (int rg2 = 0; rg2 < 2; ++rg2) {
#pragma unroll
    for (int r = 0; r < 4; ++r) {
      float v = l_acc[rg2][r];
      v += __shfl_xor(v, 1);
      v += __shfl_xor(v, 2);
      v += __shfl_xor(v, 4);
      v += __shfl_xor(v, 8);
      if (ln == 0) l_lds[32 * w + rg2 * 16 + qd * 4 + r] = v;
    }
  }
  __syncthreads();

  // ---- epilogue: out = acc / l ----
#pragma unroll
  for (int rg = 0; rg < 8; ++rg) {
#pragma unroll
    for (int r = 0; r < 4; ++r) {
      const int row = rg * 16 + qd * 4 + r;
      const float inv = 1.0f / l_lds[row];
      float* orow = out + ((size_t)b * N_ + q0 + row) * D_ + d0 + w * 64;
#pragma unroll
      for (int ct = 0; ct < 4; ++ct)
        orow[ct * 16 + ln] = acc[rg][ct][r] * inv;
    }
  }
}

// ---------------------------------------------------------------------------
// Fallback (R1, known-good fp32 fused) — used only if ws too small.
// ---------------------------------------------------------------------------
__global__ __launch_bounds__(256) void uv_gemm_f32(
    const float* __restrict__ q, const float* __restrict__ kmat,
    const float* __restrict__ Wu, const float* __restrict__ Wv,
    float* __restrict__ u, float* __restrict__ vp)
{
  __shared__ float x_lds[64][68];
  __shared__ float w_lds[64][36];
  const int t = threadIdx.x;
  const float* __restrict__ x = (blockIdx.y == 0) ? q : kmat;
  const float* __restrict__ W = (blockIdx.y == 0) ? Wu : Wv;
  float* __restrict__ o = (blockIdx.y == 0) ? u : vp;
  const int m0 = blockIdx.x * 64;
  const int row = t >> 2;
  const int c0 = (t & 3) * 8;
  float acc[8];
#pragma unroll
  for (int i = 0; i < 8; ++i) acc[i] = 0.f;
  for (int k0 = 0; k0 < D_; k0 += 64) {
#pragma unroll
    for (int i = 0; i < 4; ++i) {
      int f4 = t + i * 256;
      int r_ = f4 >> 4, cc = (f4 & 15) * 4;
      *(float4*)&x_lds[r_][cc] = *(const float4*)&x[(size_t)(m0 + r_) * D_ + k0 + cc];
    }
#pragma unroll
    for (int i = 0; i < 2; ++i) {
      int f4 = t + i * 256;
      int r_ = f4 >> 3, cc = (f4 & 7) * 4;
      *(float4*)&w_lds[r_][cc] = *(const float4*)&W[(size_t)(k0 + r_) * R_ + cc];
    }
    __syncthreads();
#pragma unroll 8
    for (int kk = 0; kk < 64; ++kk) {
      float a = x_lds[row][kk];
      float4 b0 = *(float4*)&w_lds[kk][c0];
      float4 b1 = *(float4*)&w_lds[kk][c0 + 4];
      acc[0] = fmaf(a, b0.x, acc[0]); acc[1] = fmaf(a, b0.y, acc[1]);
      acc[2] = fmaf(a, b0.z, acc[2]); acc[3] = fmaf(a, b0.w, acc[3]);
      acc[4] = fmaf(a, b1.x, acc[4]); acc[5] = fmaf(a, b1.y, acc[5]);
      acc[6] = fmaf(a, b1.z, acc[6]); acc[7] = fmaf(a, b1.w, acc[7]);
    }
    __syncthreads();
  }
  *(float4*)&o[(size_t)(m0 + row) * R_ + c0] = make_float4(acc[0], acc[1], acc[2], acc[3]);
  *(float4*)&o[(size_t)(m0 + row) * R_ + c0 + 4] = make_float4(acc[4], acc[5], acc[6], acc[7]);
}

__global__ __launch_bounds__(256) void attn_kernel(
    const float* __restrict__ u, const float* __restrict__ vp,
    const float* __restrict__ v, float* __restrict__ out)
{
  __shared__ float u_lds[64][36];
  __shared__ float vpT_lds[32][36];
  __shared__ float p_lds[64][36];
  __shared__ float v_lds[32][132];
  __shared__ float l_lds[64];
  const int t = threadIdx.x;
  const int b = blockIdx.z;
  const int m0 = blockIdx.x * 64;
  const int d0 = blockIdx.y * 128;
  const size_t rb = (size_t)b * N_;
#pragma unroll
  for (int i = 0; i < 2; ++i) {
    int f4 = t + i * 256;
    int r_ = f4 >> 3, cc = (f4 & 7) * 4;
    *(float4*)&u_lds[r_][cc] = *(const float4*)&u[(rb + m0 + r_) * R_ + cc];
  }
  const int srow = t >> 2;
  const int kc0 = (t & 3) * 8;
  const int rg = t >> 5;
  const int cx = t & 31;
  float acc[8][4];
#pragma unroll
  for (int i = 0; i < 8; ++i)
#pragma unroll
    for (int j = 0; j < 4; ++j) acc[i][j] = 0.f;
  float l_part = 0.f;
  const float scale = 0.17677669529663687f;
  for (int k0 = 0; k0 < N_; k0 += 32) {
    {
      int r_ = t >> 3, cc = (t & 7) * 4;
      float4 w4 = *(const float4*)&vp[(rb + k0 + r_) * R_ + cc];
      vpT_lds[cc + 0][r_] = w4.x; vpT_lds[cc + 1][r_] = w4.y;
      vpT_lds[cc + 2][r_] = w4.z; vpT_lds[cc + 3][r_] = w4.w;
    }
#pragma unroll
    for (int i = 0; i < 4; ++i) {
      int f4 = t + i * 256;
      int r_ = f4 >> 5, cc = (f4 & 31) * 4;
      *(float4*)&v_lds[r_][cc] = *(const float4*)&v[(rb + k0 + r_) * D_ + d0 + cc];
    }
    __syncthreads();
    float s[8];
#pragma unroll
    for (int j = 0; j < 8; ++j) s[j] = 0.f;
#pragma unroll
    for (int rr = 0; rr < 32; rr += 4) {
      float4 u4 = *(float4*)&u_lds[srow][rr];
      float ua[4] = {u4.x, u4.y, u4.z, u4.w};
#pragma unroll
      for (int q4 = 0; q4 < 4; ++q4) {
        float uu = ua[q4];
        float4 g0 = *(float4*)&vpT_lds[rr + q4][kc0];
        float4 g1 = *(float4*)&vpT_lds[rr + q4][kc0 + 4];
        s[0] = fmaf(uu, g0.x, s[0]); s[1] = fmaf(uu, g0.y, s[1]);
        s[2] = fmaf(uu, g0.z, s[2]); s[3] = fmaf(uu, g0.w, s[3]);
        s[4] = fmaf(uu, g1.x, s[4]); s[5] = fmaf(uu, g1.y, s[5]);
        s[6] = fmaf(uu, g1.z, s[6]); s[7] = fmaf(uu, g1.w, s[7]);
      }
    }
    float p[8];
    float lsum = 0.f;
#pragma unroll
    for (int j = 0; j < 8; ++j) { p[j] = __expf(s[j] * scale); lsum += p[j]; }
    l_part += lsum;
    *(float4*)&p_lds[srow][kc0] = make_float4(p[0], p[1], p[2], p[3]);
    *(float4*)&p_lds[srow][kc0 + 4] = make_float4(p[4], p[5], p[6], p[7]);
    __syncthreads();
#pragma unroll 4
    for (int kk = 0; kk < 32; ++kk) {
      float4 bv = *(float4*)&v_lds[kk][cx * 4];
#pragma unroll
      for (int i = 0; i < 8; ++i) {
        float a = p_lds[rg * 8 + i][kk];
        acc[i][0] = fmaf(a, bv.x, acc[i][0]); acc[i][1] = fmaf(a, bv.y, acc[i][1]);
        acc[i][2] = fmaf(a, bv.z, acc[i][2]); acc[i][3] = fmaf(a, bv.w, acc[i][3]);
      }
    }
    __syncthreads();
  }
  l_part += __shfl_xor(l_part, 1);
  l_part += __shfl_xor(l_part, 2);
  if ((t & 3) == 0) l_lds[srow] = l_part;
  __syncthreads();
#pragma unroll
  for (int i = 0; i < 8; ++i) {
    int row = rg * 8 + i;
    float inv = 1.0f / l_lds[row];
    *(float4*)&out[(rb + m0 + row) * D_ + d0 + cx * 4] =
        make_float4(acc[i][0] * inv, acc[i][1] * inv, acc[i][2] * inv, acc[i][3] * inv);
  }
}

// ---------------------------------------------------------------------------
extern "C" void kernel_launch(void* const* d_in, const int* in_sizes, int n_in,
                              void* d_out, int out_size, void* d_ws, size_t ws_size,
                              hipStream_t stream) {
  const float* q  = (const float*)d_in[0];
  const float* k  = (const float*)d_in[1];
  const float* v  = (const float*)d_in[2];
  const float* Wu = (const float*)d_in[3];
  const float* Wv = (const float*)d_in[4];
  float* out = (float*)d_out;

  // ws layout: u_bf 1MB | vp_bf 1MB | vT 32MiB  (~35.6 MB total)
  const size_t o_u  = 0;
  const size_t o_vp = (size_t)1 << 20;
  const size_t o_vt = (size_t)2 << 20;
  const size_t vt_bytes = (size_t)B_ * D_ * N_ * 2;
  const size_t need = o_vt + vt_bytes;

  if (ws_size >= need) {
    unsigned short* ub  = (unsigned short*)((char*)d_ws + o_u);
    unsigned short* vpb = (unsigned short*)((char*)d_ws + o_vp);
    unsigned short* vtb = (unsigned short*)((char*)d_ws + o_vt);

    uv_mfma_kernel<<<dim3(BN_ / 64, 2), 256, 0, stream>>>(q, k, Wu, Wv, ub, vpb);
    vT_kernel<<<dim3(N_ / 64, D_ / 64, B_), 256, 0, stream>>>(v, vtb);
    fused_attn_kernel<<<dim3(B_, D_ / 256, N_ / 128), 256, 0, stream>>>(
        ub, vpb, vtb, out);
  } else {
    float* uf  = (float*)d_ws;
    float* vpf = uf + (size_t)BN_ * R_;
    uv_gemm_f32<<<dim3(BN_ / 64, 2), 256, 0, stream>>>(q, k, Wu, Wv, uf, vpf);
    attn_kernel<<<dim3(N_ / 64, D_ / 128, B_), 256, 0, stream>>>(uf, vpf, v, out);
  }
}